// Round 8
// baseline (176.562 us; speedup 1.0000x reference)
//
#include <hip/hip_runtime.h>
#include <hip/hip_bf16.h>
#include <stdint.h>

typedef __bf16 bf16_t;
typedef __bf16 bf16x4 __attribute__((ext_vector_type(4)));
typedef __bf16 bf16x8 __attribute__((ext_vector_type(8)));
typedef float  f32x4  __attribute__((ext_vector_type(4)));

// async global -> LDS, 16B per lane (dest = wave-uniform base + lane*16).
__device__ __forceinline__ void gload_lds16(const void* g, void* l) {
  __builtin_amdgcn_global_load_lds(
      (__attribute__((address_space(1))) void*)g,
      (__attribute__((address_space(3))) void*)l, 16, 0, 0);
}

// ---------------- weights cast: W_enc and W_dec in one launch ----------------
__global__ void cast_weights(const float* __restrict__ a, bf16_t* __restrict__ oa,
                             const float* __restrict__ b, bf16_t* __restrict__ ob,
                             int n4each) {
  const int i = blockIdx.x * blockDim.x + threadIdx.x;
  const float* src; bf16_t* dst; int k;
  if (i < n4each) { src = a; dst = oa; k = i; }
  else            { src = b; dst = ob; k = i - n4each; }
  f32x4 v = reinterpret_cast<const f32x4*>(src)[k];
  bf16x4 o;
  o[0] = (bf16_t)v[0]; o[1] = (bf16_t)v[1]; o[2] = (bf16_t)v[2]; o[3] = (bf16_t)v[3];
  reinterpret_cast<bf16x4*>(dst)[k] = o;
}

// ============ GEMM1: 128x128 2-phase (R1 structure) + swizzle + reg-cast A + cumsum ============
// h_chunk = cumsum_128(relu(x @ W_enc^T + b_enc) * mask). M=32768 (grid.x=256, BM=128=chunk),
// N=512 (grid.y=4), K=1024. 256 thr = 4 waves (2x2 of 64x64). LDS 64KB: A dbuf 2x16KB + B dbuf 2x16KB.
__global__ __launch_bounds__(256) void gemm1_128(
    const float* __restrict__ x, const bf16_t* __restrict__ Wenc,
    const float* __restrict__ b_enc, const float* __restrict__ mask,
    bf16_t* __restrict__ h_out, float* __restrict__ partials)
{
  __shared__ __align__(16) char smem[65536];
  auto Al = [&](int buf) { return (bf16_t*)(smem + buf * 16384); };
  auto Bl = [&](int buf) { return (bf16_t*)(smem + 32768 + buf * 16384); };

  const int tid  = threadIdx.x;
  const int lane = tid & 63;
  const int w    = tid >> 6;       // 0..3
  const int wm   = w >> 1, wn = w & 1;
  const long bm  = (long)blockIdx.x * 128;
  const long bn  = (long)blockIdx.y * 128;
  const int NT   = 16;             // K=1024, BK=64

  f32x4 acc[4][4] = {};
  f32x4 av[8];                     // A reg staging: 128x64 f32 / 256 thr = 8 f32x4

  // --- A: global f32 -> regs -> cvt -> swizzled bf16 ds_write (T14, proven R4) ---
  auto gaLoad = [&](int t) {
    #pragma unroll
    for (int u = 0; u < 8; ++u) {
      const int row = u * 16 + (tid >> 4);
      av[u] = *reinterpret_cast<const f32x4*>(x + (bm + row) * 1024 + t * 64 + (tid & 15) * 4);
    }
  };
  auto aWrite = [&](int buf) {
    bf16_t* lb = Al(buf);
    const int c4 = tid & 15;
    #pragma unroll
    for (int u = 0; u < 8; ++u) {
      const int row = u * 16 + (tid >> 4);
      bf16x4 o;
      o[0] = (bf16_t)av[u][0]; o[1] = (bf16_t)av[u][1];
      o[2] = (bf16_t)av[u][2]; o[3] = (bf16_t)av[u][3];
      *reinterpret_cast<bf16x4*>(lb + row * 64 + ((((c4 >> 1) ^ (row & 7)) << 3) + (c4 & 1) * 4)) = o;
    }
  };
  // --- B: gload_lds with pre-swizzled source (involution; r0 multiple of 8) ---
  const int scolB = (((lane & 7) ^ (lane >> 3)) << 3);
  auto stageB = [&](int t, int buf) {
    bf16_t* lb = Bl(buf);
    #pragma unroll
    for (int it = 0; it < 4; ++it) {
      const int r0 = w * 32 + it * 8;
      gload_lds16(Wenc + (bn + r0 + (lane >> 3)) * 1024 + t * 64 + scolB, lb + r0 * 64);
    }
  };
  // --- fragment reads with matching swizzle; row&7 == lane&7 for all fragments ---
  auto mfma_tile = [&](int buf) {
    const bf16_t* Asb = Al(buf);
    const bf16_t* Bsb = Bl(buf);
    #pragma unroll
    for (int kk = 0; kk < 2; ++kk) {
      const int kof = (((kk * 4 + (lane >> 4)) ^ (lane & 7)) << 3);
      bf16x8 afr[4], bfr[4];
      #pragma unroll
      for (int i = 0; i < 4; ++i)
        afr[i] = *reinterpret_cast<const bf16x8*>(&Asb[(wm * 64 + i * 16 + (lane & 15)) * 64 + kof]);
      #pragma unroll
      for (int j = 0; j < 4; ++j)
        bfr[j] = *reinterpret_cast<const bf16x8*>(&Bsb[(wn * 64 + j * 16 + (lane & 15)) * 64 + kof]);
      #pragma unroll
      for (int i = 0; i < 4; ++i)
        #pragma unroll
        for (int j = 0; j < 4; ++j)
          acc[i][j] = __builtin_amdgcn_mfma_f32_16x16x32_bf16(afr[i], bfr[j], acc[i][j], 0, 0, 0);
    }
  };

  // prologue
  gaLoad(0);
  stageB(0, 0);
  aWrite(0);                                        // compiler-inserted vmcnt covers gaLoad
  asm volatile("s_waitcnt vmcnt(0)" ::: "memory");  // drain B(0)
  __syncthreads();

  // main loop: one barrier per K-tile (m97 pattern, measured 764 TF on this shape in R1)
  for (int t = 0; t < NT; ++t) {
    const int buf = t & 1;
    if (t + 1 < NT) { gaLoad(t + 1); stageB(t + 1, buf ^ 1); }
    mfma_tile(buf);
    if (t + 1 < NT) aWrite(buf ^ 1);
    asm volatile("s_waitcnt vmcnt(0)" ::: "memory");
    __syncthreads();
  }

  // ---- epilogue: relu+bias+mask -> bf16 alias tile (swizzled), then column cumsum ----
  bf16_t* tile = (bf16_t*)smem;  // [128][128] bf16, col ^ ((row&7)<<4)
  float bv[4];
  #pragma unroll
  for (int j = 0; j < 4; ++j)
    bv[j] = b_enc[bn + wn * 64 + j * 16 + (lane & 15)];

  #pragma unroll
  for (int i = 0; i < 4; ++i) {
    const int row0 = wm * 64 + i * 16 + ((lane >> 4) << 2);
    const f32x4 mv = *reinterpret_cast<const f32x4*>(&mask[bm + row0]);
    #pragma unroll
    for (int j = 0; j < 4; ++j) {
      const int col = wn * 64 + j * 16 + (lane & 15);
      #pragma unroll
      for (int e = 0; e < 4; ++e) {
        const int row = row0 + e;
        float hv = acc[i][j][e] + bv[j];
        hv = (hv > 0.f ? hv : 0.f) * mv[e];
        tile[row * 128 + (col ^ ((row & 7) << 4))] = (bf16_t)hv;
      }
    }
  }
  __syncthreads();

  // 2x-parallel column scan: half 0 = rows 0..63, half 1 = rows 64..127
  __shared__ float sum0[128];
  const int col  = tid & 127;
  const int half = tid >> 7;
  if (half == 0) {
    float s = 0.f;
    #pragma unroll 4
    for (int r = 0; r < 64; ++r)
      s += (float)tile[r * 128 + (col ^ ((r & 7) << 4))];
    sum0[col] = s;
  }
  __syncthreads();
  {
    float run = half ? sum0[col] : 0.f;
    const int rbase = half * 64;
    bf16_t* hp = h_out + (bm + rbase) * 512 + bn + col;
    #pragma unroll 4
    for (int r = 0; r < 64; ++r) {
      const int row = rbase + r;
      run += (float)tile[row * 128 + (col ^ ((row & 7) << 4))];
      hp[(long)r * 512] = (bf16_t)run;
    }
    if (half) partials[blockIdx.x * 512 + bn + col] = run;
  }
}

// ============ GEMM2: 128x128 2-phase (R1 structure) + swizzle; out = acc + P[chunk] ============
__global__ __launch_bounds__(256) void gemm2_128(
    const bf16_t* __restrict__ A, const bf16_t* __restrict__ B,
    const int K, const int N,
    const float* __restrict__ Padd,
    float* __restrict__ outf)
{
  __shared__ __align__(16) bf16_t As[2][128 * 64];
  __shared__ __align__(16) bf16_t Bs[2][128 * 64];

  const int tid  = threadIdx.x;
  const int lane = tid & 63;
  const int w    = tid >> 6;
  const int wm   = w >> 1, wn = w & 1;
  const long bm  = (long)blockIdx.x * 128;
  const long bn  = (long)blockIdx.y * 128;
  const int NT   = K >> 6;

  f32x4 acc[4][4] = {};

  const int scol = (((lane & 7) ^ (lane >> 3)) << 3);
  auto stage = [&](int t, int buf) {
    #pragma unroll
    for (int it = 0; it < 4; ++it) {
      const int r0 = w * 32 + it * 8;
      gload_lds16(A + (bm + r0 + (lane >> 3)) * (long)K + t * 64 + scol, &As[buf][r0 * 64]);
      gload_lds16(B + (bn + r0 + (lane >> 3)) * (long)K + t * 64 + scol, &Bs[buf][r0 * 64]);
    }
  };
  auto mfma_tile = [&](int buf) {
    #pragma unroll
    for (int kk = 0; kk < 2; ++kk) {
      const int kof = (((kk * 4 + (lane >> 4)) ^ (lane & 7)) << 3);
      bf16x8 afr[4], bfr[4];
      #pragma unroll
      for (int i = 0; i < 4; ++i)
        afr[i] = *reinterpret_cast<const bf16x8*>(&As[buf][(wm * 64 + i * 16 + (lane & 15)) * 64 + kof]);
      #pragma unroll
      for (int j = 0; j < 4; ++j)
        bfr[j] = *reinterpret_cast<const bf16x8*>(&Bs[buf][(wn * 64 + j * 16 + (lane & 15)) * 64 + kof]);
      #pragma unroll
      for (int i = 0; i < 4; ++i)
        #pragma unroll
        for (int j = 0; j < 4; ++j)
          acc[i][j] = __builtin_amdgcn_mfma_f32_16x16x32_bf16(afr[i], bfr[j], acc[i][j], 0, 0, 0);
    }
  };

  stage(0, 0);
  asm volatile("s_waitcnt vmcnt(0)" ::: "memory");
  __syncthreads();
  for (int t = 0; t < NT; ++t) {
    const int buf = t & 1;
    if (t + 1 < NT) stage(t + 1, buf ^ 1);
    mfma_tile(buf);
    asm volatile("s_waitcnt vmcnt(0)" ::: "memory");
    __syncthreads();
  }

  // epilogue: + per-chunk P (chunk == blockIdx.x since BM=128), f32 stores
  #pragma unroll
  for (int j = 0; j < 4; ++j) {
    const long gc = bn + wn * 64 + j * 16 + (lane & 15);
    const float pv = Padd[blockIdx.x * (long)N + gc];
    #pragma unroll
    for (int i = 0; i < 4; ++i) {
      const long gr0 = bm + wm * 64 + i * 16 + ((lane >> 4) << 2);
      #pragma unroll
      for (int e = 0; e < 4; ++e)
        outf[(gr0 + e) * (long)N + gc] = acc[i][j][e] + pv;
    }
  }
}

// ================= small B^T GEMM for P (128x128 tile, dbuf; R1-proven) ==================
__global__ __launch_bounds__(256) void gemm_p(
    const bf16_t* __restrict__ A, const bf16_t* __restrict__ B,
    const int K, const int N,
    const float* __restrict__ bias,
    float* __restrict__ outf)
{
  __shared__ __align__(16) bf16_t As[2][128 * 64];
  __shared__ __align__(16) bf16_t Bs[2][128 * 64];

  const int tid  = threadIdx.x;
  const int lane = tid & 63;
  const int w    = tid >> 6;
  const int wm   = w >> 1, wn = w & 1;
  const long bm  = (long)blockIdx.x * 128;
  const long bn  = (long)blockIdx.y * 128;

  f32x4 acc[4][4] = {};

  const int srow = w * 32 + (lane >> 3);
  const int scol = (lane & 7) * 8;
  const bf16_t* Abase = A + (bm + srow) * (long)K + scol;
  const bf16_t* Bbase = B + (bn + srow) * (long)K + scol;

  auto stage = [&](bf16_t* da, bf16_t* db, int kt) {
    #pragma unroll
    for (int it = 0; it < 4; ++it) {
      gload_lds16(Abase + (long)it * 8 * K + kt, &da[(w * 32 + it * 8) * 64]);
      gload_lds16(Bbase + (long)it * 8 * K + kt, &db[(w * 32 + it * 8) * 64]);
    }
  };
  auto mfma_tile = [&](const bf16_t* Asb, const bf16_t* Bsb) {
    #pragma unroll
    for (int kk = 0; kk < 2; ++kk) {
      const int kof = kk * 32 + (lane >> 4) * 8;
      bf16x8 afr[4], bfr[4];
      #pragma unroll
      for (int i = 0; i < 4; ++i)
        afr[i] = *reinterpret_cast<const bf16x8*>(&Asb[(wm * 64 + i * 16 + (lane & 15)) * 64 + kof]);
      #pragma unroll
      for (int j = 0; j < 4; ++j)
        bfr[j] = *reinterpret_cast<const bf16x8*>(&Bsb[(wn * 64 + j * 16 + (lane & 15)) * 64 + kof]);
      #pragma unroll
      for (int i = 0; i < 4; ++i)
        #pragma unroll
        for (int j = 0; j < 4; ++j)
          acc[i][j] = __builtin_amdgcn_mfma_f32_16x16x32_bf16(afr[i], bfr[j], acc[i][j], 0, 0, 0);
    }
  };

  stage(As[0], Bs[0], 0);
  __syncthreads();
  int kt = 64;
  for (int p2 = 0; p2 < (K >> 7); ++p2) {
    if (kt < K) stage(As[1], Bs[1], kt);
    mfma_tile(As[0], Bs[0]);
    __syncthreads();
    kt += 64;
    if (kt < K) stage(As[0], Bs[0], kt);
    mfma_tile(As[1], Bs[1]);
    __syncthreads();
    kt += 64;
  }

  #pragma unroll
  for (int j = 0; j < 4; ++j) {
    const long gc = bn + wn * 64 + j * 16 + (lane & 15);
    const float addv = bias[gc];
    #pragma unroll
    for (int i = 0; i < 4; ++i) {
      const long gr0 = bm + wm * 64 + i * 16 + ((lane >> 4) << 2);
      #pragma unroll
      for (int r = 0; r < 4; ++r)
        outf[(gr0 + r) * (long)N + gc] = acc[i][j][r] + addv;
    }
  }
}

// ------------- exclusive scan over 32 chunks per (b, o); writes v (f32) -------------
__global__ void scan_chunks(const float* __restrict__ partials, bf16_t* __restrict__ prefixb,
                            float* __restrict__ v_out) {
  const int idx = blockIdx.x * blockDim.x + threadIdx.x;  // 0..4095
  const int b = idx >> 9;
  const int o = idx & 511;
  float run = 0.f;
  #pragma unroll
  for (int c = 0; c < 32; ++c) {
    const size_t off = ((size_t)(b * 32 + c)) * 512 + o;
    prefixb[off] = (bf16_t)run;
    run += partials[off];
  }
  v_out[idx] = run;
}

extern "C" void kernel_launch(void* const* d_in, const int* in_sizes, int n_in,
                              void* d_out, int out_size, void* d_ws, size_t ws_size,
                              hipStream_t stream) {
  const float* x     = (const float*)d_in[0];   // (8,4096,1024)
  const float* mask  = (const float*)d_in[1];   // (8,4096)
  const float* W_enc = (const float*)d_in[2];   // (512,1024)
  const float* b_enc = (const float*)d_in[3];   // (512,)
  const float* W_dec = (const float*)d_in[4];   // (1024,512)
  const float* b_dec = (const float*)d_in[5];   // (1024,)

  float* out     = (float*)d_out;
  float* v_out   = out;            // 8*512
  float* out_enc = out + 4096;     // 8*4096*1024

  char* ws = (char*)d_ws;
  bf16_t* Web      = (bf16_t*)ws;  ws += (size_t)512 * 1024 * 2;    // 1 MB
  bf16_t* Wdb      = (bf16_t*)ws;  ws += (size_t)1024 * 512 * 2;    // 1 MB
  bf16_t* h        = (bf16_t*)ws;  ws += (size_t)32768 * 512 * 2;   // 33.5 MB (cumulated)
  float*  partials = (float*)ws;   ws += (size_t)256 * 512 * 4;     // 512 KB
  bf16_t* prefixb  = (bf16_t*)ws;  ws += (size_t)256 * 512 * 2;     // 256 KB
  float*  P        = (float*)ws;   ws += (size_t)256 * 1024 * 4;    // 1 MB

  // 1) cast weights (x cast fused into gemm1's A reg-staging)
  cast_weights<<<1024, 256, 0, stream>>>(W_enc, Web, W_dec, Wdb, 131072);

  // 2) GEMM1 (128² 2-phase + swizzle + reg-cast + cumsum epilogue)
  gemm1_128<<<dim3(256, 4), 256, 0, stream>>>(x, Web, b_enc, mask, h, partials);

  // 3) scan chunk sums -> exclusive prefixes (bf16) and v (f32, output 0)
  scan_chunks<<<16, 256, 0, stream>>>(partials, prefixb, v_out);

  // 4) P[r,d] = prefix[r,:] @ W_dec[d,:] + b_dec[d]   [M=256, N=1024, K=512]
  gemm_p<<<dim3(2, 8), 256, 0, stream>>>(prefixb, Wdb, 512, 1024, b_dec, P);

  // 5) GEMM2 (128² 2-phase + swizzle): out_enc = h_local @ W_dec^T + P[chunk]
  gemm2_128<<<dim3(256, 8), 256, 0, stream>>>(h, Wdb, 512, 1024, P, out_enc);
}

// Round 9
// 138.886 us; speedup vs baseline: 1.2713x; 1.2713x over previous
//
#include <hip/hip_runtime.h>
#include <hip/hip_bf16.h>
#include <stdint.h>

typedef __bf16 bf16_t;
typedef __bf16 bf16x4 __attribute__((ext_vector_type(4)));
typedef __bf16 bf16x8 __attribute__((ext_vector_type(8)));
typedef float  f32x4  __attribute__((ext_vector_type(4)));

// async global -> LDS, 16B per lane (dest = wave-uniform base + lane*16).
__device__ __forceinline__ void gload_lds16(const void* g, void* l) {
  __builtin_amdgcn_global_load_lds(
      (__attribute__((address_space(1))) void*)g,
      (__attribute__((address_space(3))) void*)l, 16, 0, 0);
}

// ---------------- weights cast: W_enc and W_dec in one launch ----------------
__global__ void cast_weights(const float* __restrict__ a, bf16_t* __restrict__ oa,
                             const float* __restrict__ b, bf16_t* __restrict__ ob,
                             int n4each) {
  const int i = blockIdx.x * blockDim.x + threadIdx.x;
  const float* src; bf16_t* dst; int k;
  if (i < n4each) { src = a; dst = oa; k = i; }
  else            { src = b; dst = ob; k = i - n4each; }
  f32x4 v = reinterpret_cast<const f32x4*>(src)[k];
  bf16x4 o;
  o[0] = (bf16_t)v[0]; o[1] = (bf16_t)v[1]; o[2] = (bf16_t)v[2]; o[3] = (bf16_t)v[3];
  reinterpret_cast<bf16x4*>(dst)[k] = o;
}

// ===================== GEMM1: BM=128 x BN=512(full N), BK=32, grid=(256,1) =====================
// h_chunk = cumsum_128(relu(x @ W_enc^T + b_enc) * mask).  x read ONCE (f32, reg-staged,
// 2-deep prefetch); W_enc loops from L2. 8 waves (2M x 4N): per-wave 64x128 out.
// LDS: A dbuf 2x8KB + B dbuf 2x64KB? no -> B tile 512x32x2B = 32KB, dbuf 2x32KB; total 80KB.
// Epilogue: 128x512 bf16 tile (128KB, aliases staging) -> per-column serial cumsum.
__global__ __launch_bounds__(512, 2) void gemm1_fn(
    const float* __restrict__ x, const bf16_t* __restrict__ Wenc,
    const float* __restrict__ b_enc, const float* __restrict__ mask,
    bf16_t* __restrict__ h_out, float* __restrict__ partials)
{
  __shared__ __align__(16) char smem[131072];
  auto Al = [&](int buf) { return (bf16_t*)(smem + buf * 8192); };            // [128][32]
  auto Bl = [&](int buf) { return (bf16_t*)(smem + 16384 + buf * 32768); };   // [512][32]

  const int tid  = threadIdx.x;
  const int lane = tid & 63;
  const int w    = tid >> 6;      // 0..7
  const int wm   = w >> 2;        // 0..1  (64-row half)
  const int wn   = w & 3;         // 0..3  (128-col quarter)
  const long bm  = (long)blockIdx.x * 128;
  const int NT   = 32;            // K=1024 / BK=32

  f32x4  acc[4][8] = {};          // [m-frag][n-frag], 128 VGPR
  bf16x8 a[4], b[8];
  f32x4  av0[2], av1[2];          // A prefetch sets (tile parity)

  // ---- A: x f32 -> regs (2 loads/thread) -> cvt -> swizzled ds_write_b128 ----
  const int arow = tid >> 2;           // 0..127
  const int ab   = tid & 3;            // 16B-block within 64B row
  auto gaLoad = [&](int t, f32x4 (&av)[2]) {
    const float* s = x + (bm + arow) * 1024 + t * 32 + ab * 8;
    av[0] = *reinterpret_cast<const f32x4*>(s);
    av[1] = *reinterpret_cast<const f32x4*>(s + 4);
  };
  auto aWrite = [&](int buf, const f32x4 (&av)[2]) {
    bf16x8 o;
    #pragma unroll
    for (int e = 0; e < 4; ++e) { o[e] = (bf16_t)av[0][e]; o[e + 4] = (bf16_t)av[1][e]; }
    const int eb = ab ^ ((arow >> 1) & 3);
    *reinterpret_cast<bf16x8*>(Al(buf) + arow * 32 + eb * 8) = o;
  };

  // ---- B: W_enc bf16 via gload_lds, source pre-swizzled (involution) ----
  auto stageB = [&](int t, int buf) {
    bf16_t* lb = Bl(buf);
    #pragma unroll
    for (int it = 0; it < 4; ++it) {
      const int r0  = w * 64 + it * 16;
      const int row = r0 + (lane >> 2);
      const int kqs = (lane & 3) ^ ((row >> 1) & 3);
      gload_lds16(Wenc + row * 1024 + t * 32 + kqs * 8, lb + r0 * 32);
    }
  };

  const int kq = lane >> 4;
  auto mfma_tile = [&](int buf) {
    const bf16_t* Asb = Al(buf);
    const bf16_t* Bsb = Bl(buf);
    #pragma unroll
    for (int fr = 0; fr < 4; ++fr) {
      const int row = wm * 64 + fr * 16 + (lane & 15);
      a[fr] = *reinterpret_cast<const bf16x8*>(Asb + row * 32 + ((kq ^ ((row >> 1) & 3)) * 8));
    }
    #pragma unroll
    for (int fn = 0; fn < 8; ++fn) {
      const int row = wn * 128 + fn * 16 + (lane & 15);
      b[fn] = *reinterpret_cast<const bf16x8*>(Bsb + row * 32 + ((kq ^ ((row >> 1) & 3)) * 8));
    }
    #pragma unroll
    for (int fr = 0; fr < 4; ++fr)
      #pragma unroll
      for (int fn = 0; fn < 8; ++fn)
        acc[fr][fn] = __builtin_amdgcn_mfma_f32_16x16x32_bf16(a[fr], b[fn], acc[fr][fn], 0, 0, 0);
  };

  // ---- prologue ----
  stageB(0, 0);             // 4 gload_lds (oldest)
  gaLoad(0, av0);           // 2
  gaLoad(1, av1);           // 2 (youngest)
  aWrite(0, av0);           // compiler waits av0 -> vmcnt(2): drains B(0) too
  asm volatile("s_waitcnt vmcnt(0) lgkmcnt(0)" ::: "memory");
  __builtin_amdgcn_s_barrier();

  // ---- main loop, unrolled x2 for static av parity (rule 20) ----
  for (int t = 0; t < NT; t += 2) {
    // even tile t: compute buf0; stage B(t+1)->buf1; load av0<-t+2; write av1->buf1
    {
      const bool g1 = (t + 1 < NT), g2 = (t + 2 < NT);
      if (g1) stageB(t + 1, 1);          // issue BEFORE gaLoad (vmcnt oldest-first drain)
      if (g2) gaLoad(t + 2, av0);
      mfma_tile(0);
      if (g1) {
        aWrite(1, av1);                  // compiler vmcnt covers av1 (issued last iter)
        if (g2) asm volatile("s_waitcnt vmcnt(2) lgkmcnt(0)" ::: "memory");
        else    asm volatile("s_waitcnt vmcnt(0) lgkmcnt(0)" ::: "memory");
        __builtin_amdgcn_s_barrier();
      }
    }
    // odd tile t+1: compute buf1; stage B(t+2)->buf0; load av1<-t+3; write av0->buf0
    {
      const bool g1 = (t + 1 < NT), g2 = (t + 2 < NT), g3 = (t + 3 < NT);
      if (g2) stageB(t + 2, 0);
      if (g3) gaLoad(t + 3, av1);
      if (g1) mfma_tile(1);
      if (g2) {
        aWrite(0, av0);
        if (g3) asm volatile("s_waitcnt vmcnt(2) lgkmcnt(0)" ::: "memory");
        else    asm volatile("s_waitcnt vmcnt(0) lgkmcnt(0)" ::: "memory");
        __builtin_amdgcn_s_barrier();
      }
    }
  }
  asm volatile("s_waitcnt vmcnt(0) lgkmcnt(0)" ::: "memory");
  __builtin_amdgcn_s_barrier();

  // ---- epilogue: relu+bias+mask -> [128][512] bf16 tile (col ^ (row&3)<<4) ----
  bf16_t* tile = (bf16_t*)smem;
  float bv[8];
  #pragma unroll
  for (int fn = 0; fn < 8; ++fn)
    bv[fn] = b_enc[wn * 128 + fn * 16 + (lane & 15)];

  #pragma unroll
  for (int fr = 0; fr < 4; ++fr) {
    const int row0 = wm * 64 + fr * 16 + ((lane >> 4) << 2);
    const f32x4 mv = *reinterpret_cast<const f32x4*>(&mask[bm + row0]);
    #pragma unroll
    for (int fn = 0; fn < 8; ++fn) {
      const int col = wn * 128 + fn * 16 + (lane & 15);
      #pragma unroll
      for (int e = 0; e < 4; ++e) {
        const int row = row0 + e;
        float hv = acc[fr][fn][e] + bv[fn];
        hv = (hv > 0.f ? hv : 0.f) * mv[e];
        tile[row * 512 + (col ^ ((row & 3) << 4))] = (bf16_t)hv;
      }
    }
  }
  __syncthreads();

  // ---- column cumsum: 512 threads = 512 cols, serial over 128 rows ----
  {
    const int col = tid;
    float run = 0.f;
    bf16_t* hp = h_out + bm * 512 + col;
    #pragma unroll 4
    for (int r = 0; r < 128; ++r) {
      run += (float)tile[r * 512 + (col ^ ((r & 3) << 4))];
      hp[(long)r * 512] = (bf16_t)run;
    }
    partials[blockIdx.x * 512 + col] = run;
  }
}

// ============ GEMM2 (R4-verbatim): out_enc = h @ W_dec^T + P[chunk], 256x256 8-phase ============
#define PHASE_SYNC() do { \
  __builtin_amdgcn_s_barrier(); \
  asm volatile("s_waitcnt lgkmcnt(0)" ::: "memory"); \
  __builtin_amdgcn_sched_barrier(0); \
  __builtin_amdgcn_s_setprio(1); \
} while (0)

#define PHASE_END() do { \
  __builtin_amdgcn_s_setprio(0); \
  __builtin_amdgcn_s_barrier(); \
} while (0)

#define QUAD(RH, CH, BF) do { \
  _Pragma("unroll") \
  for (int fr = 0; fr < 4; ++fr) { \
    _Pragma("unroll") \
    for (int fc = 0; fc < 2; ++fc) { \
      acc[RH][CH][fr][fc] = __builtin_amdgcn_mfma_f32_16x16x32_bf16(a[fr][0], BF[fc][0], acc[RH][CH][fr][fc], 0, 0, 0); \
      acc[RH][CH][fr][fc] = __builtin_amdgcn_mfma_f32_16x16x32_bf16(a[fr][1], BF[fc][1], acc[RH][CH][fr][fc], 0, 0, 0); \
    } \
  } \
} while (0)

__global__ __launch_bounds__(512, 2) void gemm2_8p(
    const bf16_t* __restrict__ A, const bf16_t* __restrict__ B,
    const int K, const int N,
    const float* __restrict__ Padd,
    float* __restrict__ outf)
{
  __shared__ __align__(16) char smem[131072];

  const int tid  = threadIdx.x;
  const int lane = tid & 63;
  const int w    = tid >> 6;
  const int wm   = w >> 2;
  const int wn   = w & 3;
  const long bm  = (long)blockIdx.x * 256;
  const long bn  = (long)blockIdx.y * 256;
  const int NT   = K >> 6;

  const int scol = (((lane & 7) ^ (lane >> 3)) << 3);
  const int fcb0 = ((((lane >> 4)    ) ^ (lane & 7)) << 3);
  const int fcb1 = ((((lane >> 4) + 4) ^ (lane & 7)) << 3);

  f32x4  acc[2][2][4][2] = {};
  bf16x8 a[4][2], b0[2][2], b1[2][2];

  auto Albs = [&](int buf) { return (bf16_t*)(smem + buf * 65536); };
  auto Blbs = [&](int buf) { return (bf16_t*)(smem + buf * 65536 + 32768); };

  auto stageA = [&](int t, int h) {
    bf16_t* lb = Albs(t & 1);
    #pragma unroll
    for (int c = 0; c < 2; ++c) {
      const int r0 = h * 128 + (w * 2 + c) * 8;
      gload_lds16(A + (bm + r0 + (lane >> 3)) * (long)K + t * 64 + scol, lb + r0 * 64);
    }
  };
  auto stageB = [&](int t, int h) {
    bf16_t* lb = Blbs(t & 1);
    #pragma unroll
    for (int c = 0; c < 2; ++c) {
      const int r0 = h * 128 + (w * 2 + c) * 8;
      gload_lds16(B + (bn + r0 + (lane >> 3)) * (long)K + t * 64 + scol, lb + r0 * 64);
    }
  };
  auto loadA = [&](int buf, int rh) {
    const bf16_t* lb = Albs(buf);
    #pragma unroll
    for (int fr = 0; fr < 4; ++fr) {
      const int row = rh * 128 + wm * 64 + fr * 16 + (lane & 15);
      a[fr][0] = *reinterpret_cast<const bf16x8*>(lb + row * 64 + fcb0);
      a[fr][1] = *reinterpret_cast<const bf16x8*>(lb + row * 64 + fcb1);
    }
  };
  auto loadB = [&](int buf, int ch, bf16x8 (&bf)[2][2]) {
    const bf16_t* lb = Blbs(buf);
    #pragma unroll
    for (int fc = 0; fc < 2; ++fc) {
      const int row = ch * 128 + wn * 32 + fc * 16 + (lane & 15);
      bf[fc][0] = *reinterpret_cast<const bf16x8*>(lb + row * 64 + fcb0);
      bf[fc][1] = *reinterpret_cast<const bf16x8*>(lb + row * 64 + fcb1);
    }
  };

  __builtin_amdgcn_sched_barrier(0);
  stageA(0, 0); stageA(0, 1); stageB(0, 0); stageB(0, 1);
  stageA(1, 0); stageA(1, 1); stageB(1, 0); stageB(1, 1);
  asm volatile("s_waitcnt vmcnt(8)" ::: "memory");
  __builtin_amdgcn_s_barrier();

  for (int t = 0; t < NT; ++t) {
    const int buf = t & 1;
    const bool g2 = (t + 2 < NT);

    loadA(buf, 0); loadB(buf, 0, b0);
    PHASE_SYNC(); QUAD(0, 0, b0); PHASE_END();

    loadB(buf, 1, b1);
    if (g2) stageA(t + 2, 0);
    PHASE_SYNC(); QUAD(0, 1, b1); PHASE_END();

    loadA(buf, 1);
    if (g2) stageB(t + 2, 0);
    PHASE_SYNC(); QUAD(1, 0, b0); PHASE_END();

    if (g2) { stageA(t + 2, 1); stageB(t + 2, 1); }
    PHASE_SYNC(); QUAD(1, 1, b1);
    __builtin_amdgcn_s_setprio(0);
    if (g2) asm volatile("s_waitcnt vmcnt(8)" ::: "memory");
    else    asm volatile("s_waitcnt vmcnt(0)" ::: "memory");
    __builtin_amdgcn_s_barrier();
  }
  __builtin_amdgcn_sched_barrier(0);

  #pragma unroll
  for (int rh = 0; rh < 2; ++rh)
    #pragma unroll
    for (int ch = 0; ch < 2; ++ch)
      #pragma unroll
      for (int fc = 0; fc < 2; ++fc) {
        const long gc = bn + ch * 128 + wn * 32 + fc * 16 + (lane & 15);
        const float pv = Padd[(blockIdx.x * 2 + rh) * (long)N + gc];
        #pragma unroll
        for (int fr = 0; fr < 4; ++fr) {
          const long gr = bm + rh * 128 + wm * 64 + fr * 16 + ((lane >> 4) << 2);
          #pragma unroll
          for (int e = 0; e < 4; ++e)
            outf[(gr + e) * (long)N + gc] = acc[rh][ch][fr][fc][e] + pv;
        }
      }
}

// ================= small B^T GEMM for P (128x128 tile, dbuf) ==================
__global__ __launch_bounds__(256) void gemm_p(
    const bf16_t* __restrict__ A, const bf16_t* __restrict__ B,
    const int K, const int N,
    const float* __restrict__ bias,
    float* __restrict__ outf)
{
  __shared__ __align__(16) bf16_t As[2][128 * 64];
  __shared__ __align__(16) bf16_t Bs[2][128 * 64];

  const int tid  = threadIdx.x;
  const int lane = tid & 63;
  const int w    = tid >> 6;
  const int wm   = w >> 1, wn = w & 1;
  const long bm  = (long)blockIdx.x * 128;
  const long bn  = (long)blockIdx.y * 128;

  f32x4 acc[4][4] = {};

  const int srow = w * 32 + (lane >> 3);
  const int scol = (lane & 7) * 8;
  const bf16_t* Abase = A + (bm + srow) * (long)K + scol;
  const bf16_t* Bbase = B + (bn + srow) * (long)K + scol;

  auto stage = [&](bf16_t* da, bf16_t* db, int kt) {
    #pragma unroll
    for (int it = 0; it < 4; ++it) {
      gload_lds16(Abase + (long)it * 8 * K + kt, &da[(w * 32 + it * 8) * 64]);
      gload_lds16(Bbase + (long)it * 8 * K + kt, &db[(w * 32 + it * 8) * 64]);
    }
  };
  auto mfma_tile = [&](const bf16_t* Asb, const bf16_t* Bsb) {
    #pragma unroll
    for (int kk = 0; kk < 2; ++kk) {
      const int kof = kk * 32 + (lane >> 4) * 8;
      bf16x8 afr[4], bfr[4];
      #pragma unroll
      for (int i = 0; i < 4; ++i)
        afr[i] = *reinterpret_cast<const bf16x8*>(&Asb[(wm * 64 + i * 16 + (lane & 15)) * 64 + kof]);
      #pragma unroll
      for (int j = 0; j < 4; ++j)
        bfr[j] = *reinterpret_cast<const bf16x8*>(&Bsb[(wn * 64 + j * 16 + (lane & 15)) * 64 + kof]);
      #pragma unroll
      for (int i = 0; i < 4; ++i)
        #pragma unroll
        for (int j = 0; j < 4; ++j)
          acc[i][j] = __builtin_amdgcn_mfma_f32_16x16x32_bf16(afr[i], bfr[j], acc[i][j], 0, 0, 0);
    }
  };

  stage(As[0], Bs[0], 0);
  __syncthreads();
  int kt = 64;
  for (int p2 = 0; p2 < (K >> 7); ++p2) {
    if (kt < K) stage(As[1], Bs[1], kt);
    mfma_tile(As[0], Bs[0]);
    __syncthreads();
    kt += 64;
    if (kt < K) stage(As[0], Bs[0], kt);
    mfma_tile(As[1], Bs[1]);
    __syncthreads();
    kt += 64;
  }

  #pragma unroll
  for (int j = 0; j < 4; ++j) {
    const long gc = bn + wn * 64 + j * 16 + (lane & 15);
    const float addv = bias[gc];
    #pragma unroll
    for (int i = 0; i < 4; ++i) {
      const long gr0 = bm + wm * 64 + i * 16 + ((lane >> 4) << 2);
      #pragma unroll
      for (int r = 0; r < 4; ++r)
        outf[(gr0 + r) * (long)N + gc] = acc[i][j][r] + addv;
    }
  }
}

// ------------- exclusive scan over 32 chunks per (b, o); writes v (f32) -------------
__global__ void scan_chunks(const float* __restrict__ partials, bf16_t* __restrict__ prefixb,
                            float* __restrict__ v_out) {
  const int idx = blockIdx.x * blockDim.x + threadIdx.x;  // 0..4095
  const int b = idx >> 9;
  const int o = idx & 511;
  float run = 0.f;
  #pragma unroll
  for (int c = 0; c < 32; ++c) {
    const size_t off = ((size_t)(b * 32 + c)) * 512 + o;
    prefixb[off] = (bf16_t)run;
    run += partials[off];
  }
  v_out[idx] = run;
}

extern "C" void kernel_launch(void* const* d_in, const int* in_sizes, int n_in,
                              void* d_out, int out_size, void* d_ws, size_t ws_size,
                              hipStream_t stream) {
  const float* x     = (const float*)d_in[0];   // (8,4096,1024)
  const float* mask  = (const float*)d_in[1];   // (8,4096)
  const float* W_enc = (const float*)d_in[2];   // (512,1024)
  const float* b_enc = (const float*)d_in[3];   // (512,)
  const float* W_dec = (const float*)d_in[4];   // (1024,512)
  const float* b_dec = (const float*)d_in[5];   // (1024,)

  float* out     = (float*)d_out;
  float* v_out   = out;            // 8*512
  float* out_enc = out + 4096;     // 8*4096*1024

  char* ws = (char*)d_ws;
  bf16_t* Web      = (bf16_t*)ws;  ws += (size_t)512 * 1024 * 2;    // 1 MB
  bf16_t* Wdb      = (bf16_t*)ws;  ws += (size_t)1024 * 512 * 2;    // 1 MB
  bf16_t* h        = (bf16_t*)ws;  ws += (size_t)32768 * 512 * 2;   // 33.5 MB (cumulated)
  float*  partials = (float*)ws;   ws += (size_t)256 * 512 * 4;     // 512 KB
  bf16_t* prefixb  = (bf16_t*)ws;  ws += (size_t)256 * 512 * 2;     // 256 KB
  float*  P        = (float*)ws;   ws += (size_t)256 * 1024 * 4;    // 1 MB

  // 1) cast weights (x cast fused into gemm1's A reg-staging)
  cast_weights<<<1024, 256, 0, stream>>>(W_enc, Web, W_dec, Wdb, 131072);

  // 2) GEMM1 full-N: h = cumsum_128(relu(x @ W_enc^T + b_enc) * mask); x read once
  gemm1_fn<<<dim3(256, 1), 512, 0, stream>>>(x, Web, b_enc, mask, h, partials);

  // 3) scan chunk sums -> exclusive prefixes (bf16) and v (f32, output 0)
  scan_chunks<<<16, 256, 0, stream>>>(partials, prefixb, v_out);

  // 4) P[r,d] = prefix[r,:] @ W_dec[d,:] + b_dec[d]   [M=256, N=1024, K=512]
  gemm_p<<<dim3(2, 8), 256, 0, stream>>>(prefixb, Wdb, 512, 1024, b_dec, P);

  // 5) GEMM2 (R4-verbatim 8-phase): out_enc = h_local @ W_dec^T + P[chunk]
  gemm2_8p<<<dim3(128, 4), 512, 0, stream>>>(h, Wdb, 512, 1024, P, out_enc);
}